// Round 1
// baseline (926.359 us; speedup 1.0000x reference)
//
#include <hip/hip_runtime.h>
#include <math.h>

#define GB 64      // graphs in batch
#define AD 8       // n_actions

// ---- deg init: self-loop weight 1.0 for every node ----
__global__ void k_init_deg(float* deg, int n) {
    int i = blockIdx.x * blockDim.x + threadIdx.x;
    if (i < n) deg[i] = 1.0f;
}

// ---- edge MLP -> w, accumulate weighted in-degree at dst ----
__global__ void k_edge_w(const int* __restrict__ ei, const float* __restrict__ attr,
                         const float* __restrict__ W_e1, const float* __restrict__ b_e1,
                         const float* __restrict__ W_e2, const float* __restrict__ b_e2,
                         float* __restrict__ w_edge, float* __restrict__ deg, int E) {
    int e = blockIdx.x * blockDim.x + threadIdx.x;
    if (e >= E) return;
    float s = (float)ei[e];
    float d = (float)ei[E + e];
    float a = attr[e];
    float h = s * W_e1[0] + d * W_e1[1] + a * W_e1[2] + b_e1[0];
    h = fmaxf(h, 0.0f);
    float z = h * W_e2[0] + b_e2[0];
    float w = 1.0f / (1.0f + expf(-z));
    w_edge[e] = w;
    atomicAdd(&deg[ei[E + e]], w);
}

// ---- deg -> deg^{-1/2} in place (deg >= 1 always) ----
__global__ void k_dis(float* deg, int n) {
    int i = blockIdx.x * blockDim.x + threadIdx.x;
    if (i < n) deg[i] = 1.0f / sqrtf(deg[i]);
}

// ---- xw = x @ W_gcn  (M=50000, K=128, N=128 fp32, vector ALU) ----
__global__ __launch_bounds__(256) void k_xw(const float* __restrict__ x,
                                            const float* __restrict__ Wg,
                                            float* __restrict__ xw, int n) {
    __shared__ float xs[16 * 128];
    int block_row = blockIdx.x * 16;
    int tid = threadIdx.x;
    #pragma unroll
    for (int i = 0; i < 8; i++) {
        int idx = tid + i * 256;                 // 0..2047
        int r = idx >> 7, c = idx & 127;
        int gr = block_row + r;
        xs[idx] = (gr < n) ? x[(size_t)gr * 128 + c] : 0.0f;
    }
    __syncthreads();
    int c = tid & 127;
    int rbase = (tid >> 7) * 8;
    float acc[8] = {0, 0, 0, 0, 0, 0, 0, 0};
    for (int k = 0; k < 128; k++) {
        float wv = Wg[k * 128 + c];              // coalesced; L1/L2-resident (64 KB)
        #pragma unroll
        for (int r = 0; r < 8; r++)
            acc[r] += xs[(rbase + r) * 128 + k] * wv;  // LDS broadcast (same addr)
    }
    #pragma unroll
    for (int r = 0; r < 8; r++) {
        int gr = block_row + rbase + r;
        if (gr < n) xw[(size_t)gr * 128 + c] = acc[r];
    }
}

// ---- message scatter: conv[dst] += dis[src]*w*dis[dst] * xw[src] ----
__global__ __launch_bounds__(256) void k_msg(const int* __restrict__ ei,
                                             const float* __restrict__ w_edge,
                                             const float* __restrict__ dis,
                                             const float* __restrict__ xw,
                                             float* __restrict__ conv, int E) {
    int f  = threadIdx.x & 127;
    int eo = threadIdx.x >> 7;
    int base = blockIdx.x * 8;
    #pragma unroll
    for (int it = 0; it < 4; it++) {
        int e = base + it * 2 + eo;
        if (e < E) {
            int s = ei[e];
            int d = ei[E + e];
            float nrm = dis[s] * w_edge[e] * dis[d];
            float v = nrm * xw[(size_t)s * 128 + f];
            atomicAdd(&conv[(size_t)d * 128 + f], v);
        }
    }
}

// ---- h1 = relu(conv + dis^2 * xw + b_gcn), in place into conv ----
__global__ void k_h1(const float* __restrict__ xw, const float* __restrict__ dis,
                     const float* __restrict__ bg, float* __restrict__ conv, int n) {
    int idx = blockIdx.x * blockDim.x + threadIdx.x;
    if (idx >= n * 128) return;
    int i = idx >> 7, f = idx & 127;
    float di = dis[i];
    float v = conv[idx] + di * di * xw[idx] + bg[f];
    conv[idx] = fmaxf(v, 0.0f);
}

// ---- mean-pool: batch is sorted -> running accumulate, flush on change ----
__global__ __launch_bounds__(128) void k_pool(const float* __restrict__ h1,
                                              const int* __restrict__ batch,
                                              float* __restrict__ psum,
                                              float* __restrict__ pcnt, int n) {
    int f = threadIdx.x;
    int n0 = blockIdx.x * 64;
    if (n0 >= n) return;
    int n1 = min(n0 + 64, n);
    int cur = batch[n0];
    float acc = 0.0f, cnt = 0.0f;
    for (int i = n0; i < n1; i++) {
        int g = batch[i];
        if (g != cur) {
            atomicAdd(&psum[cur * 128 + f], acc);
            if (f == 0) atomicAdd(&pcnt[cur], cnt);
            acc = 0.0f; cnt = 0.0f; cur = g;
        }
        acc += h1[(size_t)i * 128 + f];
        cnt += 1.0f;
    }
    atomicAdd(&psum[cur * 128 + f], acc);
    if (f == 0) atomicAdd(&pcnt[cur], cnt);
}

// ---- head: pooled = psum/cnt; h2 = relu(pooled@W2+b2); out = h2@W3+b3 ----
__global__ __launch_bounds__(128) void k_head(const float* __restrict__ psum,
                                              const float* __restrict__ pcnt,
                                              const float* __restrict__ W2,
                                              const float* __restrict__ b2,
                                              const float* __restrict__ W3,
                                              const float* __restrict__ b3,
                                              float* __restrict__ out) {
    __shared__ float pl[128];
    __shared__ float h2s[128];
    int g = blockIdx.x;
    int t = threadIdx.x;
    float c = fmaxf(pcnt[g], 1.0f);
    pl[t] = psum[g * 128 + t] / c;
    __syncthreads();
    float acc = b2[t];
    for (int k = 0; k < 128; k++) acc += pl[k] * W2[k * 128 + t];
    h2s[t] = fmaxf(acc, 0.0f);
    __syncthreads();
    if (t < AD) {
        float o = b3[t];
        for (int k = 0; k < 128; k++) o += h2s[k] * W3[k * AD + t];
        out[g * AD + t] = o;
    }
}

extern "C" void kernel_launch(void* const* d_in, const int* in_sizes, int n_in,
                              void* d_out, int out_size, void* d_ws, size_t ws_size,
                              hipStream_t stream) {
    const float* x        = (const float*)d_in[0];
    const float* edge_attr= (const float*)d_in[1];
    const float* W_e1     = (const float*)d_in[2];
    const float* b_e1     = (const float*)d_in[3];
    const float* W_e2     = (const float*)d_in[4];
    const float* b_e2     = (const float*)d_in[5];
    const float* W_gcn    = (const float*)d_in[6];
    const float* b_gcn    = (const float*)d_in[7];
    const float* W2       = (const float*)d_in[8];
    const float* b2       = (const float*)d_in[9];
    const float* W3       = (const float*)d_in[10];
    const float* b3       = (const float*)d_in[11];
    const int*   ei       = (const int*)d_in[12];
    const int*   batch    = (const int*)d_in[13];
    float* out = (float*)d_out;

    const int E = in_sizes[12] / 2;   // 1,600,000
    const int n = in_sizes[13];       // 50,000

    // workspace layout (floats)
    float* ws     = (float*)d_ws;
    float* w_edge = ws;                          // E
    float* deg    = w_edge + E;                  // n  (becomes dis in place)
    float* xw     = deg + n;                     // n*128
    float* conv   = xw + (size_t)n * 128;        // n*128
    float* psum   = conv + (size_t)n * 128;      // GB*128
    float* pcnt   = psum + GB * 128;             // GB

    hipMemsetAsync(conv, 0, (size_t)n * 128 * sizeof(float), stream);
    hipMemsetAsync(psum, 0, (GB * 128 + GB) * sizeof(float), stream);

    k_init_deg<<<(n + 255) / 256, 256, 0, stream>>>(deg, n);
    k_edge_w<<<(E + 255) / 256, 256, 0, stream>>>(ei, edge_attr, W_e1, b_e1, W_e2, b_e2,
                                                  w_edge, deg, E);
    k_dis<<<(n + 255) / 256, 256, 0, stream>>>(deg, n);
    k_xw<<<(n + 15) / 16, 256, 0, stream>>>(x, W_gcn, xw, n);
    k_msg<<<(E + 7) / 8, 256, 0, stream>>>(ei, w_edge, deg, xw, conv, E);
    k_h1<<<((size_t)n * 128 + 255) / 256, 256, 0, stream>>>(xw, deg, b_gcn, conv, n);
    k_pool<<<(n + 63) / 64, 128, 0, stream>>>(conv, batch, psum, pcnt, n);
    k_head<<<GB, 128, 0, stream>>>(psum, pcnt, W2, b2, W3, b3, out);
}

// Round 2
// 539.289 us; speedup vs baseline: 1.7177x; 1.7177x over previous
//
#include <hip/hip_runtime.h>
#include <math.h>

#define GB 64      // graphs in batch
#define AD 8       // n_actions

// ---- deg init: self-loop weight 1.0 for every node ----
__global__ void k_init_deg(float* deg, int n) {
    int i = blockIdx.x * blockDim.x + threadIdx.x;
    if (i < n) deg[i] = 1.0f;
}

// ---- edge MLP -> w; accumulate weighted in-degree + in-degree count at dst ----
__global__ void k_edge_w(const int* __restrict__ ei, const float* __restrict__ attr,
                         const float* __restrict__ W_e1, const float* __restrict__ b_e1,
                         const float* __restrict__ W_e2, const float* __restrict__ b_e2,
                         float* __restrict__ deg, int* __restrict__ cnt, int E) {
    int e = blockIdx.x * blockDim.x + threadIdx.x;
    if (e >= E) return;
    float s = (float)ei[e];
    float d = (float)ei[E + e];
    float a = attr[e];
    float h = s * W_e1[0] + d * W_e1[1] + a * W_e1[2] + b_e1[0];
    h = fmaxf(h, 0.0f);
    float z = h * W_e2[0] + b_e2[0];
    float w = 1.0f / (1.0f + expf(-z));
    int dst = ei[E + e];
    atomicAdd(&deg[dst], w);
    atomicAdd(&cnt[dst], 1);
}

// ---- deg -> deg^{-1/2} in place (deg >= 1 always, self-loop) ----
__global__ void k_dis(float* deg, int n) {
    int i = blockIdx.x * blockDim.x + threadIdx.x;
    if (i < n) deg[i] = 1.0f / sqrtf(deg[i]);
}

// ---- scan step 1: per-block (256-wide) sums of cnt ----
__global__ __launch_bounds__(256) void k_scan1(const int* __restrict__ cnt,
                                               int* __restrict__ bsum, int n) {
    __shared__ int sm[256];
    int t = threadIdx.x;
    int i = blockIdx.x * 256 + t;
    sm[t] = (i < n) ? cnt[i] : 0;
    __syncthreads();
    for (int s = 128; s > 0; s >>= 1) {
        if (t < s) sm[t] += sm[t + s];
        __syncthreads();
    }
    if (t == 0) bsum[blockIdx.x] = sm[0];
}

// ---- scan step 2: exclusive scan of block sums (nb <= 256), single block ----
__global__ __launch_bounds__(256) void k_scan2(int* bsum, int nb) {
    __shared__ int sm[256];
    int t = threadIdx.x;
    int v = (t < nb) ? bsum[t] : 0;
    sm[t] = v;
    __syncthreads();
    for (int s = 1; s < 256; s <<= 1) {
        int tmp = (t >= s) ? sm[t - s] : 0;
        __syncthreads();
        sm[t] += tmp;
        __syncthreads();
    }
    if (t < nb) bsum[t] = sm[t] - v;   // exclusive
}

// ---- scan step 3: rowptr[i] = exclusive_scan(cnt)[i] ----
__global__ __launch_bounds__(256) void k_scan3(const int* __restrict__ cnt,
                                               const int* __restrict__ bsum,
                                               int* __restrict__ rowptr, int n) {
    __shared__ int sm[256];
    int t = threadIdx.x;
    int i = blockIdx.x * 256 + t;
    int v = (i < n) ? cnt[i] : 0;
    sm[t] = v;
    __syncthreads();
    for (int s = 1; s < 256; s <<= 1) {
        int tmp = (t >= s) ? sm[t - s] : 0;
        __syncthreads();
        sm[t] += tmp;
        __syncthreads();
    }
    if (i < n) rowptr[i] = sm[t] - v + bsum[blockIdx.x];
}

// ---- fill CSR buckets: rec[pos] = (src, nrm). rowptr becomes INCLUSIVE. ----
__global__ void k_fill(const int* __restrict__ ei, const float* __restrict__ attr,
                       const float* __restrict__ W_e1, const float* __restrict__ b_e1,
                       const float* __restrict__ W_e2, const float* __restrict__ b_e2,
                       const float* __restrict__ dis, int* __restrict__ rowptr,
                       int2* __restrict__ rec, int E) {
    int e = blockIdx.x * blockDim.x + threadIdx.x;
    if (e >= E) return;
    int s = ei[e];
    int d = ei[E + e];
    float sf = (float)s, df = (float)d;
    float h = sf * W_e1[0] + df * W_e1[1] + attr[e] * W_e1[2] + b_e1[0];
    h = fmaxf(h, 0.0f);
    float z = h * W_e2[0] + b_e2[0];
    float w = 1.0f / (1.0f + expf(-z));
    float nrm = dis[s] * w * dis[d];
    int pos = atomicAdd(&rowptr[d], 1);
    int2 r;
    r.x = s;
    r.y = __float_as_int(nrm);
    rec[pos] = r;
}

// ---- xw = x @ W_gcn  (M=50000, K=128, N=128 fp32, vector ALU) ----
__global__ __launch_bounds__(256) void k_xw(const float* __restrict__ x,
                                            const float* __restrict__ Wg,
                                            float* __restrict__ xw, int n) {
    __shared__ float xs[16 * 128];
    int block_row = blockIdx.x * 16;
    int tid = threadIdx.x;
    #pragma unroll
    for (int i = 0; i < 8; i++) {
        int idx = tid + i * 256;
        int r = idx >> 7, c = idx & 127;
        int gr = block_row + r;
        xs[idx] = (gr < n) ? x[(size_t)gr * 128 + c] : 0.0f;
    }
    __syncthreads();
    int c = tid & 127;
    int rbase = (tid >> 7) * 8;
    float acc[8] = {0, 0, 0, 0, 0, 0, 0, 0};
    for (int k = 0; k < 128; k++) {
        float wv = Wg[k * 128 + c];
        #pragma unroll
        for (int r = 0; r < 8; r++)
            acc[r] += xs[(rbase + r) * 128 + k] * wv;
    }
    #pragma unroll
    for (int r = 0; r < 8; r++) {
        int gr = block_row + rbase + r;
        if (gr < n) xw[(size_t)gr * 128 + c] = acc[r];
    }
}

// ---- gather: h1[i] = relu(sum_in nrm*xw[src] + dis^2*xw[i] + b_gcn) ----
// one block (128 threads) per node; thread f = feature f; single coalesced write
__global__ __launch_bounds__(128) void k_gather(const int2* __restrict__ rec,
                                                const int* __restrict__ rowptr_incl,
                                                const int* __restrict__ cnt,
                                                const float* __restrict__ dis,
                                                const float* __restrict__ xw,
                                                const float* __restrict__ bg,
                                                float* __restrict__ conv, int n) {
    __shared__ int2 sm[128];
    int i = blockIdx.x;
    int f = threadIdx.x;
    int end = rowptr_incl[i];     // after k_fill, rowptr is inclusive
    int deg = cnt[i];
    int start = end - deg;
    float di = dis[i];
    float acc = di * di * xw[(size_t)i * 128 + f];
    for (int base = start; base < end; base += 128) {
        int m = min(128, end - base);
        if (f < m) sm[f] = rec[base + f];
        __syncthreads();
        for (int j = 0; j < m; j++) {
            int s = sm[j].x;
            float nrm = __int_as_float(sm[j].y);
            acc += nrm * xw[(size_t)s * 128 + f];
        }
        __syncthreads();
    }
    conv[(size_t)i * 128 + f] = fmaxf(acc + bg[f], 0.0f);
}

// ---- mean-pool: batch sorted -> running accumulate, flush on change ----
__global__ __launch_bounds__(128) void k_pool(const float* __restrict__ h1,
                                              const int* __restrict__ batch,
                                              float* __restrict__ psum,
                                              float* __restrict__ pcnt, int n) {
    int f = threadIdx.x;
    int n0 = blockIdx.x * 64;
    if (n0 >= n) return;
    int n1 = min(n0 + 64, n);
    int cur = batch[n0];
    float acc = 0.0f, cnt = 0.0f;
    for (int i = n0; i < n1; i++) {
        int g = batch[i];
        if (g != cur) {
            atomicAdd(&psum[cur * 128 + f], acc);
            if (f == 0) atomicAdd(&pcnt[cur], cnt);
            acc = 0.0f; cnt = 0.0f; cur = g;
        }
        acc += h1[(size_t)i * 128 + f];
        cnt += 1.0f;
    }
    atomicAdd(&psum[cur * 128 + f], acc);
    if (f == 0) atomicAdd(&pcnt[cur], cnt);
}

// ---- head: pooled = psum/cnt; h2 = relu(pooled@W2+b2); out = h2@W3+b3 ----
__global__ __launch_bounds__(128) void k_head(const float* __restrict__ psum,
                                              const float* __restrict__ pcnt,
                                              const float* __restrict__ W2,
                                              const float* __restrict__ b2,
                                              const float* __restrict__ W3,
                                              const float* __restrict__ b3,
                                              float* __restrict__ out) {
    __shared__ float pl[128];
    __shared__ float h2s[128];
    int g = blockIdx.x;
    int t = threadIdx.x;
    float c = fmaxf(pcnt[g], 1.0f);
    pl[t] = psum[g * 128 + t] / c;
    __syncthreads();
    float acc = b2[t];
    for (int k = 0; k < 128; k++) acc += pl[k] * W2[k * 128 + t];
    h2s[t] = fmaxf(acc, 0.0f);
    __syncthreads();
    if (t < AD) {
        float o = b3[t];
        for (int k = 0; k < 128; k++) o += h2s[k] * W3[k * AD + t];
        out[g * AD + t] = o;
    }
}

extern "C" void kernel_launch(void* const* d_in, const int* in_sizes, int n_in,
                              void* d_out, int out_size, void* d_ws, size_t ws_size,
                              hipStream_t stream) {
    const float* x        = (const float*)d_in[0];
    const float* edge_attr= (const float*)d_in[1];
    const float* W_e1     = (const float*)d_in[2];
    const float* b_e1     = (const float*)d_in[3];
    const float* W_e2     = (const float*)d_in[4];
    const float* b_e2     = (const float*)d_in[5];
    const float* W_gcn    = (const float*)d_in[6];
    const float* b_gcn    = (const float*)d_in[7];
    const float* W2       = (const float*)d_in[8];
    const float* b2       = (const float*)d_in[9];
    const float* W3       = (const float*)d_in[10];
    const float* b3       = (const float*)d_in[11];
    const int*   ei       = (const int*)d_in[12];
    const int*   batch    = (const int*)d_in[13];
    float* out = (float*)d_out;

    const int E = in_sizes[12] / 2;   // 1,600,000
    const int n = in_sizes[13];       // 50,000
    const int nb = (n + 255) / 256;   // scan blocks (196)

    // workspace layout
    char* p = (char*)d_ws;
    float* deg    = (float*)p;               p += (size_t)n * sizeof(float);        // -> dis
    float* xw     = (float*)p;               p += (size_t)n * 128 * sizeof(float);
    float* conv   = (float*)p;               p += (size_t)n * 128 * sizeof(float);
    float* psum   = (float*)p;               p += (size_t)GB * 128 * sizeof(float);
    float* pcnt   = (float*)p;               p += (size_t)GB * sizeof(float);
    int*   cnt    = (int*)p;                 p += (size_t)n * sizeof(int);
    int*   rowptr = (int*)p;                 p += (size_t)n * sizeof(int);
    int*   bsum   = (int*)p;                 p += (size_t)256 * sizeof(int);
    int2*  rec    = (int2*)p;                p += (size_t)E * sizeof(int2);

    hipMemsetAsync(cnt, 0, (size_t)n * sizeof(int), stream);
    hipMemsetAsync(psum, 0, (GB * 128 + GB) * sizeof(float), stream);

    k_init_deg<<<(n + 255) / 256, 256, 0, stream>>>(deg, n);
    k_edge_w<<<(E + 255) / 256, 256, 0, stream>>>(ei, edge_attr, W_e1, b_e1, W_e2, b_e2,
                                                  deg, cnt, E);
    k_dis<<<(n + 255) / 256, 256, 0, stream>>>(deg, n);
    k_scan1<<<nb, 256, 0, stream>>>(cnt, bsum, n);
    k_scan2<<<1, 256, 0, stream>>>(bsum, nb);
    k_scan3<<<nb, 256, 0, stream>>>(cnt, bsum, rowptr, n);
    k_fill<<<(E + 255) / 256, 256, 0, stream>>>(ei, edge_attr, W_e1, b_e1, W_e2, b_e2,
                                                deg, rowptr, rec, E);
    k_xw<<<(n + 15) / 16, 256, 0, stream>>>(x, W_gcn, xw, n);
    k_gather<<<n, 128, 0, stream>>>(rec, rowptr, cnt, deg, xw, b_gcn, conv, n);
    k_pool<<<(n + 63) / 64, 128, 0, stream>>>(conv, batch, psum, pcnt, n);
    k_head<<<GB, 128, 0, stream>>>(psum, pcnt, W2, b2, W3, b3, out);
}

// Round 3
// 445.735 us; speedup vs baseline: 2.0783x; 1.2099x over previous
//
#include <hip/hip_runtime.h>
#include <math.h>

#define GB 64       // graphs in batch
#define AD 8        // n_actions
#define NC 128      // edge chunks
#define RR 4        // dst-range passes
#define RBMAX 13000 // max bins per range (52 KB LDS)

// ---- pass 1: per-chunk LDS histogram of dst, written chunk-major ----
__global__ __launch_bounds__(256) void k_hist(const int* __restrict__ ei,
                                              int* __restrict__ H,
                                              int E, int n, int ce, int rb) {
    __shared__ int h[RBMAX];
    int c = blockIdx.x, r = blockIdx.y;
    int lo = r * rb, hi = min(lo + rb, n), nb = hi - lo;
    for (int b = threadIdx.x; b < nb; b += 256) h[b] = 0;
    __syncthreads();
    int e0 = c * ce, e1 = min(e0 + ce, E);
    for (int e = e0 + threadIdx.x; e < e1; e += 256) {
        int d = ei[E + e];
        if (d >= lo && d < hi) atomicAdd(&h[d - lo], 1);   // LDS atomic
    }
    __syncthreads();
    for (int b = threadIdx.x; b < nb; b += 256)
        H[(size_t)c * n + lo + b] = h[b];                  // coalesced
}

// ---- pass 2: per-bin exclusive prefix across chunks (in place) + totals ----
__global__ __launch_bounds__(256) void k_colpref(int* __restrict__ H,
                                                 int* __restrict__ cnt,
                                                 int n, int nc) {
    int bin = blockIdx.x * 256 + threadIdx.x;
    if (bin >= n) return;
    int s = 0;
    for (int c = 0; c < nc; c++) {
        size_t idx = (size_t)c * n + bin;   // coalesced across threads
        int v = H[idx];
        H[idx] = s;
        s += v;
    }
    cnt[bin] = s;
}

// ---- scan step 1: per-block (256-wide) sums of cnt ----
__global__ __launch_bounds__(256) void k_scan1(const int* __restrict__ cnt,
                                               int* __restrict__ bsum, int n) {
    __shared__ int sm[256];
    int t = threadIdx.x;
    int i = blockIdx.x * 256 + t;
    sm[t] = (i < n) ? cnt[i] : 0;
    __syncthreads();
    for (int s = 128; s > 0; s >>= 1) {
        if (t < s) sm[t] += sm[t + s];
        __syncthreads();
    }
    if (t == 0) bsum[blockIdx.x] = sm[0];
}

// ---- scan step 2: exclusive scan of block sums (nb <= 256), single block ----
__global__ __launch_bounds__(256) void k_scan2(int* bsum, int nb) {
    __shared__ int sm[256];
    int t = threadIdx.x;
    int v = (t < nb) ? bsum[t] : 0;
    sm[t] = v;
    __syncthreads();
    for (int s = 1; s < 256; s <<= 1) {
        int tmp = (t >= s) ? sm[t - s] : 0;
        __syncthreads();
        sm[t] += tmp;
        __syncthreads();
    }
    if (t < nb) bsum[t] = sm[t] - v;   // exclusive
}

// ---- scan step 3: rowptr[i] = exclusive_scan(cnt)[i] ----
__global__ __launch_bounds__(256) void k_scan3(const int* __restrict__ cnt,
                                               const int* __restrict__ bsum,
                                               int* __restrict__ rowptr, int n) {
    __shared__ int sm[256];
    int t = threadIdx.x;
    int i = blockIdx.x * 256 + t;
    int v = (i < n) ? cnt[i] : 0;
    sm[t] = v;
    __syncthreads();
    for (int s = 1; s < 256; s <<= 1) {
        int tmp = (t >= s) ? sm[t - s] : 0;
        __syncthreads();
        sm[t] += tmp;
        __syncthreads();
    }
    if (i < n) rowptr[i] = sm[t] - v + bsum[blockIdx.x];
}

// ---- pass 3: fill CSR records (src, w) using LDS slot allocation ----
__global__ __launch_bounds__(256) void k_fill(const int* __restrict__ ei,
                                              const float* __restrict__ attr,
                                              const float* __restrict__ W_e1,
                                              const float* __restrict__ b_e1,
                                              const float* __restrict__ W_e2,
                                              const float* __restrict__ b_e2,
                                              const int* __restrict__ rowptr,
                                              const int* __restrict__ H,
                                              int2* __restrict__ rec,
                                              int E, int n, int ce, int rb) {
    __shared__ int off[RBMAX];
    int c = blockIdx.x, r = blockIdx.y;
    int lo = r * rb, hi = min(lo + rb, n), nb = hi - lo;
    for (int b = threadIdx.x; b < nb; b += 256)
        off[b] = rowptr[lo + b] + H[(size_t)c * n + lo + b];
    __syncthreads();
    float w1s = W_e1[0], w1d = W_e1[1], w1a = W_e1[2], bb1 = b_e1[0];
    float w2 = W_e2[0], bb2 = b_e2[0];
    int e0 = c * ce, e1 = min(e0 + ce, E);
    for (int e = e0 + threadIdx.x; e < e1; e += 256) {
        int d = ei[E + e];
        if (d >= lo && d < hi) {
            int s = ei[e];
            float h = (float)s * w1s + (float)d * w1d + attr[e] * w1a + bb1;
            h = fmaxf(h, 0.0f);
            float w = 1.0f / (1.0f + expf(-(h * w2 + bb2)));
            int pos = atomicAdd(&off[d - lo], 1);          // LDS atomic
            int2 rv; rv.x = s; rv.y = __float_as_int(w);
            rec[pos] = rv;
        }
    }
}

// ---- deg from CSR: dis[i] = rsqrt(1 + sum_j w_j) — no atomics ----
__global__ void k_deg(const int2* __restrict__ rec, const int* __restrict__ rowptr,
                      const int* __restrict__ cnt, float* __restrict__ dis, int n) {
    int i = blockIdx.x * 256 + threadIdx.x;
    if (i >= n) return;
    int st = rowptr[i], en = st + cnt[i];
    float deg = 1.0f;
    for (int j = st; j < en; j++) deg += __int_as_float(rec[j].y);
    dis[i] = rsqrtf(deg);
}

// ---- xw = x @ W_gcn  (M=50000, K=128, N=128 fp32, vector ALU) ----
__global__ __launch_bounds__(256) void k_xw(const float* __restrict__ x,
                                            const float* __restrict__ Wg,
                                            float* __restrict__ xw, int n) {
    __shared__ float xs[16 * 128];
    int block_row = blockIdx.x * 16;
    int tid = threadIdx.x;
    #pragma unroll
    for (int i = 0; i < 8; i++) {
        int idx = tid + i * 256;
        int r = idx >> 7, c = idx & 127;
        int gr = block_row + r;
        xs[idx] = (gr < n) ? x[(size_t)gr * 128 + c] : 0.0f;
    }
    __syncthreads();
    int c = tid & 127;
    int rbase = (tid >> 7) * 8;
    float acc[8] = {0, 0, 0, 0, 0, 0, 0, 0};
    for (int k = 0; k < 128; k++) {
        float wv = Wg[k * 128 + c];
        #pragma unroll
        for (int r = 0; r < 8; r++)
            acc[r] += xs[(rbase + r) * 128 + k] * wv;
    }
    #pragma unroll
    for (int r = 0; r < 8; r++) {
        int gr = block_row + rbase + r;
        if (gr < n) xw[(size_t)gr * 128 + c] = acc[r];
    }
}

// ---- gather: h1[i] = relu(dis_i*(sum w*dis_s*xw[s] + dis_i*xw[i]) + bg) ----
__global__ __launch_bounds__(128) void k_gather(const int2* __restrict__ rec,
                                                const int* __restrict__ rowptr,
                                                const int* __restrict__ cnt,
                                                const float* __restrict__ dis,
                                                const float* __restrict__ xw,
                                                const float* __restrict__ bg,
                                                float* __restrict__ conv, int n) {
    __shared__ int ssrc[128];
    __shared__ float scoef[128];
    int i = blockIdx.x;
    int f = threadIdx.x;
    int st = rowptr[i];
    int m = cnt[i];
    float di = dis[i];
    float acc = di * xw[(size_t)i * 128 + f];   // self-loop (outer di applied at end)
    for (int base = 0; base < m; base += 128) {
        int k = min(128, m - base);
        if (f < k) {
            int2 rv = rec[st + base + f];
            ssrc[f] = rv.x;
            scoef[f] = __int_as_float(rv.y) * dis[rv.x];
        }
        __syncthreads();
        for (int j = 0; j < k; j++)
            acc += scoef[j] * xw[(size_t)ssrc[j] * 128 + f];
        __syncthreads();
    }
    conv[(size_t)i * 128 + f] = fmaxf(di * acc + bg[f], 0.0f);
}

// ---- mean-pool: batch sorted -> running accumulate, flush on change ----
__global__ __launch_bounds__(128) void k_pool(const float* __restrict__ h1,
                                              const int* __restrict__ batch,
                                              float* __restrict__ psum,
                                              float* __restrict__ pcnt, int n) {
    int f = threadIdx.x;
    int n0 = blockIdx.x * 64;
    if (n0 >= n) return;
    int n1 = min(n0 + 64, n);
    int cur = batch[n0];
    float acc = 0.0f, cnt = 0.0f;
    for (int i = n0; i < n1; i++) {
        int g = batch[i];
        if (g != cur) {
            atomicAdd(&psum[cur * 128 + f], acc);
            if (f == 0) atomicAdd(&pcnt[cur], cnt);
            acc = 0.0f; cnt = 0.0f; cur = g;
        }
        acc += h1[(size_t)i * 128 + f];
        cnt += 1.0f;
    }
    atomicAdd(&psum[cur * 128 + f], acc);
    if (f == 0) atomicAdd(&pcnt[cur], cnt);
}

// ---- head: pooled = psum/cnt; h2 = relu(pooled@W2+b2); out = h2@W3+b3 ----
__global__ __launch_bounds__(128) void k_head(const float* __restrict__ psum,
                                              const float* __restrict__ pcnt,
                                              const float* __restrict__ W2,
                                              const float* __restrict__ b2,
                                              const float* __restrict__ W3,
                                              const float* __restrict__ b3,
                                              float* __restrict__ out) {
    __shared__ float pl[128];
    __shared__ float h2s[128];
    int g = blockIdx.x;
    int t = threadIdx.x;
    float c = fmaxf(pcnt[g], 1.0f);
    pl[t] = psum[g * 128 + t] / c;
    __syncthreads();
    float acc = b2[t];
    for (int k = 0; k < 128; k++) acc += pl[k] * W2[k * 128 + t];
    h2s[t] = fmaxf(acc, 0.0f);
    __syncthreads();
    if (t < AD) {
        float o = b3[t];
        for (int k = 0; k < 128; k++) o += h2s[k] * W3[k * AD + t];
        out[g * AD + t] = o;
    }
}

extern "C" void kernel_launch(void* const* d_in, const int* in_sizes, int n_in,
                              void* d_out, int out_size, void* d_ws, size_t ws_size,
                              hipStream_t stream) {
    const float* x        = (const float*)d_in[0];
    const float* edge_attr= (const float*)d_in[1];
    const float* W_e1     = (const float*)d_in[2];
    const float* b_e1     = (const float*)d_in[3];
    const float* W_e2     = (const float*)d_in[4];
    const float* b_e2     = (const float*)d_in[5];
    const float* W_gcn    = (const float*)d_in[6];
    const float* b_gcn    = (const float*)d_in[7];
    const float* W2       = (const float*)d_in[8];
    const float* b2       = (const float*)d_in[9];
    const float* W3       = (const float*)d_in[10];
    const float* b3       = (const float*)d_in[11];
    const int*   ei       = (const int*)d_in[12];
    const int*   batch    = (const int*)d_in[13];
    float* out = (float*)d_out;

    const int E = in_sizes[12] / 2;        // 1,600,000
    const int n = in_sizes[13];            // 50,000
    const int nb = (n + 255) / 256;        // scan blocks (196)
    const int ce = (E + NC - 1) / NC;      // edges per chunk (12,500)
    const int rb = (n + RR - 1) / RR;      // bins per range pass (12,500 <= RBMAX)

    // workspace layout
    char* p = (char*)d_ws;
    float* dis    = (float*)p;  p += (size_t)n * sizeof(float);
    float* xw     = (float*)p;  p += (size_t)n * 128 * sizeof(float);
    int*   H      = (int*)p;    p += (size_t)NC * n * sizeof(int);    // 25.6 MB
    float* conv   = (float*)H;                                        // aliases H (H dead after k_fill)
    float* psum   = (float*)p;  p += (size_t)GB * 128 * sizeof(float);
    float* pcnt   = (float*)p;  p += (size_t)GB * sizeof(float);
    int*   cnt    = (int*)p;    p += (size_t)n * sizeof(int);
    int*   rowptr = (int*)p;    p += (size_t)n * sizeof(int);
    int*   bsum   = (int*)p;    p += (size_t)256 * sizeof(int);
    int2*  rec    = (int2*)p;   p += (size_t)E * sizeof(int2);

    hipMemsetAsync(psum, 0, (GB * 128 + GB) * sizeof(float), stream);

    k_xw<<<(n + 15) / 16, 256, 0, stream>>>(x, W_gcn, xw, n);
    k_hist<<<dim3(NC, RR), 256, 0, stream>>>(ei, H, E, n, ce, rb);
    k_colpref<<<nb, 256, 0, stream>>>(H, cnt, n, NC);
    k_scan1<<<nb, 256, 0, stream>>>(cnt, bsum, n);
    k_scan2<<<1, 256, 0, stream>>>(bsum, nb);
    k_scan3<<<nb, 256, 0, stream>>>(cnt, bsum, rowptr, n);
    k_fill<<<dim3(NC, RR), 256, 0, stream>>>(ei, edge_attr, W_e1, b_e1, W_e2, b_e2,
                                             rowptr, H, rec, E, n, ce, rb);
    k_deg<<<nb, 256, 0, stream>>>(rec, rowptr, cnt, dis, n);
    k_gather<<<n, 128, 0, stream>>>(rec, rowptr, cnt, dis, xw, b_gcn, conv, n);
    k_pool<<<(n + 63) / 64, 128, 0, stream>>>(conv, batch, psum, pcnt, n);
    k_head<<<GB, 128, 0, stream>>>(psum, pcnt, W2, b2, W3, b3, out);
}

// Round 4
// 429.690 us; speedup vs baseline: 2.1559x; 1.0373x over previous
//
#include <hip/hip_runtime.h>
#include <hip/hip_fp16.h>
#include <math.h>

#define GB 64       // graphs in batch
#define AD 8        // n_actions
#define NC 64       // edge chunks
#define RR 4        // dst-range passes
#define RBMAX 13000 // max bins per range pass (52 KB LDS)

// ---- pass 1: per-chunk LDS histogram of dst, written chunk-major ----
__global__ __launch_bounds__(256) void k_hist(const int* __restrict__ ei,
                                              int* __restrict__ H,
                                              int E, int n, int ce, int rb) {
    __shared__ int h[RBMAX];
    int c = blockIdx.x, r = blockIdx.y;
    int lo = r * rb, hi = min(lo + rb, n), nb = hi - lo;
    for (int b = threadIdx.x; b < nb; b += 256) h[b] = 0;
    __syncthreads();
    int e0 = c * ce, e1 = min(e0 + ce, E);
    for (int e = e0 + threadIdx.x; e < e1; e += 256) {
        int d = ei[E + e];
        if (d >= lo && d < hi) atomicAdd(&h[d - lo], 1);   // LDS atomic
    }
    __syncthreads();
    for (int b = threadIdx.x; b < nb; b += 256)
        H[(size_t)c * n + lo + b] = h[b];                  // coalesced
}

// ---- pass 2: per-bin exclusive prefix across chunks + totals + block sums ----
__global__ __launch_bounds__(256) void k_colpref(int* __restrict__ H,
                                                 int* __restrict__ cnt,
                                                 int* __restrict__ bsum,
                                                 int n, int nc) {
    __shared__ int sm[256];
    int t = threadIdx.x;
    int bin = blockIdx.x * 256 + t;
    int s = 0;
    if (bin < n) {
        for (int c = 0; c < nc; c++) {
            size_t idx = (size_t)c * n + bin;   // coalesced across threads
            int v = H[idx];
            H[idx] = s;
            s += v;
        }
        cnt[bin] = s;
    }
    sm[t] = (bin < n) ? s : 0;
    __syncthreads();
    for (int r = 128; r > 0; r >>= 1) {
        if (t < r) sm[t] += sm[t + r];
        __syncthreads();
    }
    if (t == 0) bsum[blockIdx.x] = sm[0];
}

// ---- scan step 2: exclusive scan of block sums (nb <= 256), single block ----
__global__ __launch_bounds__(256) void k_scan2(int* bsum, int nb) {
    __shared__ int sm[256];
    int t = threadIdx.x;
    int v = (t < nb) ? bsum[t] : 0;
    sm[t] = v;
    __syncthreads();
    for (int s = 1; s < 256; s <<= 1) {
        int tmp = (t >= s) ? sm[t - s] : 0;
        __syncthreads();
        sm[t] += tmp;
        __syncthreads();
    }
    if (t < nb) bsum[t] = sm[t] - v;   // exclusive
}

// ---- scan step 3: rowptr[i] = exclusive_scan(cnt)[i] ----
__global__ __launch_bounds__(256) void k_scan3(const int* __restrict__ cnt,
                                               const int* __restrict__ bsum,
                                               int* __restrict__ rowptr, int n) {
    __shared__ int sm[256];
    int t = threadIdx.x;
    int i = blockIdx.x * 256 + t;
    int v = (i < n) ? cnt[i] : 0;
    sm[t] = v;
    __syncthreads();
    for (int s = 1; s < 256; s <<= 1) {
        int tmp = (t >= s) ? sm[t - s] : 0;
        __syncthreads();
        sm[t] += tmp;
        __syncthreads();
    }
    if (i < n) rowptr[i] = sm[t] - v + bsum[blockIdx.x];
}

// ---- pass 3: fill CSR records (src, w) using LDS slot allocation ----
__global__ __launch_bounds__(256) void k_fill(const int* __restrict__ ei,
                                              const float* __restrict__ attr,
                                              const float* __restrict__ W_e1,
                                              const float* __restrict__ b_e1,
                                              const float* __restrict__ W_e2,
                                              const float* __restrict__ b_e2,
                                              const int* __restrict__ rowptr,
                                              const int* __restrict__ H,
                                              int2* __restrict__ rec,
                                              int E, int n, int ce, int rb) {
    __shared__ int off[RBMAX];
    int c = blockIdx.x, r = blockIdx.y;
    int lo = r * rb, hi = min(lo + rb, n), nb = hi - lo;
    for (int b = threadIdx.x; b < nb; b += 256)
        off[b] = rowptr[lo + b] + H[(size_t)c * n + lo + b];
    __syncthreads();
    float w1s = W_e1[0], w1d = W_e1[1], w1a = W_e1[2], bb1 = b_e1[0];
    float w2 = W_e2[0], bb2 = b_e2[0];
    int e0 = c * ce, e1 = min(e0 + ce, E);
    for (int e = e0 + threadIdx.x; e < e1; e += 256) {
        int d = ei[E + e];
        if (d >= lo && d < hi) {
            int s = ei[e];
            float h = (float)s * w1s + (float)d * w1d + attr[e] * w1a + bb1;
            h = fmaxf(h, 0.0f);
            float w = 1.0f / (1.0f + expf(-(h * w2 + bb2)));
            int pos = atomicAdd(&off[d - lo], 1);          // LDS atomic
            int2 rv; rv.x = s; rv.y = __float_as_int(w);
            rec[pos] = rv;
        }
    }
}

// ---- deg from CSR: dis[i] = rsqrt(1 + sum_j w_j) — no atomics ----
__global__ void k_deg(const int2* __restrict__ rec, const int* __restrict__ rowptr,
                      const int* __restrict__ cnt, float* __restrict__ dis, int n) {
    int i = blockIdx.x * 256 + threadIdx.x;
    if (i >= n) return;
    int st = rowptr[i], en = st + cnt[i];
    float deg = 1.0f;
    for (int j = st; j < en; j++) deg += __int_as_float(rec[j].y);
    dis[i] = rsqrtf(deg);
}

// ---- xw = x @ W_gcn, stored fp16 (M=50000, K=128, N=128) ----
__global__ __launch_bounds__(256) void k_xw(const float* __restrict__ x,
                                            const float* __restrict__ Wg,
                                            __half* __restrict__ xwh, int n) {
    __shared__ float xs[16 * 128];
    int block_row = blockIdx.x * 16;
    int tid = threadIdx.x;
    #pragma unroll
    for (int i = 0; i < 8; i++) {
        int idx = tid + i * 256;
        int r = idx >> 7, c = idx & 127;
        int gr = block_row + r;
        xs[idx] = (gr < n) ? x[(size_t)gr * 128 + c] : 0.0f;
    }
    __syncthreads();
    int c = tid & 127;
    int rbase = (tid >> 7) * 8;
    float acc[8] = {0, 0, 0, 0, 0, 0, 0, 0};
    for (int k = 0; k < 128; k++) {
        float wv = Wg[k * 128 + c];
        #pragma unroll
        for (int r = 0; r < 8; r++)
            acc[r] += xs[(rbase + r) * 128 + k] * wv;
    }
    #pragma unroll
    for (int r = 0; r < 8; r++) {
        int gr = block_row + rbase + r;
        if (gr < n) xwh[(size_t)gr * 128 + c] = __float2half(acc[r]);
    }
}

// ---- gather: one wave per node; lane owns half2 feature pair ----
// h1[i] = relu(di*(sum w*dis_s*xw[s] + di*xw[i]) + bg)
__global__ __launch_bounds__(256) void k_gather(const int2* __restrict__ rec,
                                                const int* __restrict__ rowptr,
                                                const int* __restrict__ cnt,
                                                const float* __restrict__ dis,
                                                const __half2* __restrict__ xh,
                                                const float* __restrict__ bg,
                                                float* __restrict__ conv, int n) {
    int wave = threadIdx.x >> 6;
    int lane = threadIdx.x & 63;
    int i = blockIdx.x * 4 + wave;
    if (i >= n) return;                     // wave-uniform
    int st = rowptr[i];
    int m = cnt[i];
    float di = dis[i];
    float2 self = __half22float2(xh[(size_t)i * 64 + lane]);
    float ax = di * self.x, ay = di * self.y;   // outer di applied at end
    for (int base = 0; base < m; base += 64) {
        int k = min(64, m - base);
        int sv = 0; float cf = 0.0f;
        if (lane < k) {
            int2 rv = rec[st + base + lane];
            sv = rv.x;
            cf = __int_as_float(rv.y) * dis[rv.x];
        }
        #pragma unroll 4
        for (int j = 0; j < k; j++) {
            int s = __builtin_amdgcn_readlane(sv, j);
            float cw = __int_as_float(__builtin_amdgcn_readlane(__float_as_int(cf), j));
            float2 v = __half22float2(xh[(size_t)s * 64 + lane]);
            ax += cw * v.x;
            ay += cw * v.y;
        }
    }
    float2 bgl = ((const float2*)bg)[lane];
    float2 o;
    o.x = fmaxf(di * ax + bgl.x, 0.0f);
    o.y = fmaxf(di * ay + bgl.y, 0.0f);
    ((float2*)conv)[(size_t)i * 64 + lane] = o;
}

// ---- mean-pool: batch sorted -> running accumulate, flush on change ----
__global__ __launch_bounds__(128) void k_pool(const float* __restrict__ h1,
                                              const int* __restrict__ batch,
                                              float* __restrict__ psum,
                                              float* __restrict__ pcnt, int n) {
    int f = threadIdx.x;
    int n0 = blockIdx.x * 64;
    if (n0 >= n) return;
    int n1 = min(n0 + 64, n);
    int cur = batch[n0];
    float acc = 0.0f, cnt = 0.0f;
    for (int i = n0; i < n1; i++) {
        int g = batch[i];
        if (g != cur) {
            atomicAdd(&psum[cur * 128 + f], acc);
            if (f == 0) atomicAdd(&pcnt[cur], cnt);
            acc = 0.0f; cnt = 0.0f; cur = g;
        }
        acc += h1[(size_t)i * 128 + f];
        cnt += 1.0f;
    }
    atomicAdd(&psum[cur * 128 + f], acc);
    if (f == 0) atomicAdd(&pcnt[cur], cnt);
}

// ---- head: pooled = psum/cnt; h2 = relu(pooled@W2+b2); out = h2@W3+b3 ----
__global__ __launch_bounds__(128) void k_head(const float* __restrict__ psum,
                                              const float* __restrict__ pcnt,
                                              const float* __restrict__ W2,
                                              const float* __restrict__ b2,
                                              const float* __restrict__ W3,
                                              const float* __restrict__ b3,
                                              float* __restrict__ out) {
    __shared__ float pl[128];
    __shared__ float h2s[128];
    int g = blockIdx.x;
    int t = threadIdx.x;
    float c = fmaxf(pcnt[g], 1.0f);
    pl[t] = psum[g * 128 + t] / c;
    __syncthreads();
    float acc = b2[t];
    for (int k = 0; k < 128; k++) acc += pl[k] * W2[k * 128 + t];
    h2s[t] = fmaxf(acc, 0.0f);
    __syncthreads();
    if (t < AD) {
        float o = b3[t];
        for (int k = 0; k < 128; k++) o += h2s[k] * W3[k * AD + t];
        out[g * AD + t] = o;
    }
}

extern "C" void kernel_launch(void* const* d_in, const int* in_sizes, int n_in,
                              void* d_out, int out_size, void* d_ws, size_t ws_size,
                              hipStream_t stream) {
    const float* x        = (const float*)d_in[0];
    const float* edge_attr= (const float*)d_in[1];
    const float* W_e1     = (const float*)d_in[2];
    const float* b_e1     = (const float*)d_in[3];
    const float* W_e2     = (const float*)d_in[4];
    const float* b_e2     = (const float*)d_in[5];
    const float* W_gcn    = (const float*)d_in[6];
    const float* b_gcn    = (const float*)d_in[7];
    const float* W2       = (const float*)d_in[8];
    const float* b2       = (const float*)d_in[9];
    const float* W3       = (const float*)d_in[10];
    const float* b3       = (const float*)d_in[11];
    const int*   ei       = (const int*)d_in[12];
    const int*   batch    = (const int*)d_in[13];
    float* out = (float*)d_out;

    const int E = in_sizes[12] / 2;        // 1,600,000
    const int n = in_sizes[13];            // 50,000
    const int nb = (n + 255) / 256;        // 196
    const int ce = (E + NC - 1) / NC;      // 25,000 edges per chunk
    const int rb = (n + RR - 1) / RR;      // 12,500 bins per range (<= RBMAX)

    // workspace layout (~52 MB)
    char* p = (char*)d_ws;
    float*   dis  = (float*)p;   p += (size_t)n * sizeof(float);
    __half*  xwh  = (__half*)p;  p += (size_t)n * 128 * sizeof(__half);
    // H (NC*n*4 = 12.8 MB) lives inside conv's region (n*128*4 = 25.6 MB); H dead before gather
    int*     H    = (int*)p;
    float*   conv = (float*)p;   p += (size_t)n * 128 * sizeof(float);
    float*   psum = (float*)p;   p += (size_t)GB * 128 * sizeof(float);
    float*   pcnt = (float*)p;   p += (size_t)GB * sizeof(float);
    int*     cnt  = (int*)p;     p += (size_t)n * sizeof(int);
    int*     rowptr = (int*)p;   p += (size_t)n * sizeof(int);
    int*     bsum = (int*)p;     p += (size_t)256 * sizeof(int);
    int2*    rec  = (int2*)p;    p += (size_t)E * sizeof(int2);

    hipMemsetAsync(psum, 0, (GB * 128 + GB) * sizeof(float), stream);

    k_xw<<<(n + 15) / 16, 256, 0, stream>>>(x, W_gcn, xwh, n);
    k_hist<<<dim3(NC, RR), 256, 0, stream>>>(ei, H, E, n, ce, rb);
    k_colpref<<<nb, 256, 0, stream>>>(H, cnt, bsum, n, NC);
    k_scan2<<<1, 256, 0, stream>>>(bsum, nb);
    k_scan3<<<nb, 256, 0, stream>>>(cnt, bsum, rowptr, n);
    k_fill<<<dim3(NC, RR), 256, 0, stream>>>(ei, edge_attr, W_e1, b_e1, W_e2, b_e2,
                                             rowptr, H, rec, E, n, ce, rb);
    k_deg<<<nb, 256, 0, stream>>>(rec, rowptr, cnt, dis, n);
    k_gather<<<(n + 3) / 4, 256, 0, stream>>>(rec, rowptr, cnt, dis, xwh ? (const __half2*)xwh : nullptr,
                                              b_gcn, conv, n);
    k_pool<<<(n + 63) / 64, 128, 0, stream>>>(conv, batch, psum, pcnt, n);
    k_head<<<GB, 128, 0, stream>>>(psum, pcnt, W2, b2, W3, b3, out);
}